// Round 12
// baseline (593.948 us; speedup 1.0000x reference)
//
#include <hip/hip_runtime.h>

#define CT 16
#define NN 20000
#define EE 320000
#define MM 48
#define RR 4
#define EMM 256
#define NRANGE 64
#define NPR 313           // ceil(NN/64); buckets 0..62 have 313 nodes, bucket 63 has 281
#define CAP 5632          // per-bucket capacity (mean ~5008, sigma ~70 -> +9 sigma)
#define MAGIC 13721941ULL // ceil(2^32/313); floor(d/313) = (d*MAGIC)>>32, exact for d<2^20

// workspace layout (float offsets)
#define OFF_MEANX 0               // 3072
#define OFF_P     3072            // 9216 -> 12288
#define OFF_CNTD  12288           // CT*64 = 1024 ints
#define OFF_CNTS  13312           // 1024 ints -> 14336
#define ZERO_FLOATS 14336         // meanx+p+cnt zeroed by k_prep
#define OFF_COMB  14336           // CT*NN*8 ({a_d trio, 1/den trio} per node)
#define OFF_AS    2574336         // CT*NN*4
#define OFF_AD    3854336         // CT*NN*4
#define OFF_U     5134336         // 9216
#define OFF_V     5143552         // 9216
#define OFF_MX    5152768         // 9216
#define OFF_HH    5161984         // 36864
#define OFF_OUTS  5198848         // 36864
#define OFF_BIND  5235712         // CT*64*CAP ints
#define OFF_BINS  11002880        // CT*64*CAP ints
#define OFF_W     16770048        // 48*48 (W1^100; rows 16..47 written by k_front role C)
#define OFF_MX2   16772352        // 48*192 (tissue-applied mx)
// total = 16781568 floats = 67.1 MB

__device__ inline unsigned bucket_of(int d) {
    return (unsigned)(((unsigned long long)(unsigned)d * MAGIC) >> 32);
}

// ---- K1: fold att vectors through lin; also zeroes the small accumulators.
__global__ __launch_bounds__(192) void k_prep(const float* __restrict__ lin,
        const float* __restrict__ as_g, const float* __restrict__ ad_g,
        float* __restrict__ U, float* __restrict__ V, float* __restrict__ zws) {
    int c = blockIdx.x, d = threadIdx.x;
    int gt = c * 192 + d;
    for (int o = gt; o < ZERO_FLOATS; o += 16 * 192) zws[o] = 0.f;
    const float* L  = lin + ((size_t)c * 192 + d) * 192;
    const float* As = as_g + c * 192;
    const float* Ad = ad_g + c * 192;
#pragma unroll
    for (int h = 0; h < 3; ++h) {
        float u = 0.f, v = 0.f;
        for (int j = 0; j < 64; ++j) {
            float lv = L[h * 64 + j];
            u += lv * As[h * 64 + j];
            v += lv * Ad[h * 64 + j];
        }
        U[c * 576 + h * 192 + d] = u;
        V[c * 576 + h * 192 + d] = v;
    }
}

// ---- K_front: fused independent front work + tissue W1^100 (role C, block 0).
// Block 0: role C (W power, 32x48 bottom-block representation, 12.3 KB LDS).
// Blocks [1,1025): edge binning. Blocks [1025,3025): a_s/a_d projection.
// 3025 blocks vs 2048 resident slots: round 2 is half-empty, so the extra
// role-C block rides free; as block 0 it starts at t=0 and hides fully.
__global__ __launch_bounds__(256) void k_front(const int* __restrict__ edges,
        int* __restrict__ cntD, int* __restrict__ cntS,
        int* __restrict__ binD, int* __restrict__ binS,
        const float* __restrict__ x, const float* __restrict__ U,
        const float* __restrict__ V, float* __restrict__ a_s,
        float* __restrict__ a_d, float* __restrict__ meanx,
        const int* __restrict__ nb, float* __restrict__ Wout) {
    __shared__ __align__(16) float smem[3456];   // 13.8 KB, max of all roles
    int tid = threadIdx.x;
    if (blockIdx.x == 0) {
        // ---- role C: W1^100. Rows 0..15 of W1 are identity forever, so only
        // the 32x48 bottom block is stored; identity-top is folded into the
        // multiply: C[i,j] = A[i,j]*[j<16] + sum_t A[i,16+t]*B[t,j].
        float* P  = smem;          // [32][48] running power
        float* Rm = smem + 1536;   // [32][48] result
        for (int o = tid; o < 1536; o += 256) {
            int i = o / 48, j = o - i * 48;
            float idv = (j == 16 + i) ? 1.f : 0.f;
            P[o] = idv;            // pre-sweep: identity bottom
            Rm[o] = idv;           // R = I
        }
        __syncthreads();
        if (tid < 48) {
            int j = tid;  // lane owns column j: Gauss-Seidel deps intra-lane
            for (int t = 0; t < 32; ++t) {
                float acc = 0.f;
#pragma unroll
                for (int k = 0; k < 8; ++k) {
                    int idx = nb[t * 8 + k];
                    acc += (idx < 16) ? (j == idx ? 1.f : 0.f)
                                      : P[(idx - 16) * 48 + j];
                }
                P[t * 48 + j] = acc * 0.125f;
            }
        }
        __syncthreads();
        int e = 100;
        float r[6];
        while (e) {
            if (e & 1) {  // R = R x P
#pragma unroll
                for (int q = 0; q < 6; ++q) {
                    int o = tid + q * 256;
                    int i = o / 48, j = o - i * 48;
                    float acc = (j < 16) ? Rm[i * 48 + j] : 0.f;
                    for (int t = 0; t < 32; ++t) acc += Rm[i * 48 + 16 + t] * P[t * 48 + j];
                    r[q] = acc;
                }
                __syncthreads();
#pragma unroll
                for (int q = 0; q < 6; ++q) Rm[tid + q * 256] = r[q];
                __syncthreads();
            }
            e >>= 1;
            if (e) {      // P = P x P
#pragma unroll
                for (int q = 0; q < 6; ++q) {
                    int o = tid + q * 256;
                    int i = o / 48, j = o - i * 48;
                    float acc = (j < 16) ? P[i * 48 + j] : 0.f;
                    for (int t = 0; t < 32; ++t) acc += P[i * 48 + 16 + t] * P[t * 48 + j];
                    r[q] = acc;
                }
                __syncthreads();
#pragma unroll
                for (int q = 0; q < 6; ++q) P[tid + q * 256] = r[q];
                __syncthreads();
            }
        }
        for (int o = tid; o < 1536; o += 256) {
            int i = o / 48, j = o - i * 48;
            Wout[(16 + i) * 48 + j] = Rm[o];   // only rows 16..47 are consumed
        }
    } else if (blockIdx.x < 1025) {
        // ---- role A: bin2 ----
        int wg = blockIdx.x - 1;
        int ct = (wg & 7) * 2 + ((wg >> 3) & 1);  // XCD-pinned celltype
        int part = wg >> 4;                       // 0..63, chunk = 5000 edges
        int wave = tid >> 6;
        int* histD = (int*)smem;                  // [4][64]
        int* histS = histD + 256;                 // [4][64]
        int* curD  = histS + 256;                 // [64]
        int* curS  = curD + 64;                   // [64]
        if (tid < NRANGE) {
            histD[0 * 64 + tid] = 0; histD[1 * 64 + tid] = 0;
            histD[2 * 64 + tid] = 0; histD[3 * 64 + tid] = 0;
            histS[0 * 64 + tid] = 0; histS[1 * 64 + tid] = 0;
            histS[2 * 64 + tid] = 0; histS[3 * 64 + tid] = 0;
        }
        __syncthreads();
        const int* srcp = edges + (size_t)ct * 2 * EE;
        const int* dstp = srcp + EE;
        const int4* s4 = (const int4*)srcp;
        const int4* d4 = (const int4*)dstp;
        int base4 = part * 1250;
        for (int i = tid; i < 1250; i += 256) {
            int4 dv = d4[base4 + i];
            int4 sv = s4[base4 + i];
            atomicAdd(&histD[wave * 64 + bucket_of(dv.x)], 1);
            atomicAdd(&histD[wave * 64 + bucket_of(dv.y)], 1);
            atomicAdd(&histD[wave * 64 + bucket_of(dv.z)], 1);
            atomicAdd(&histD[wave * 64 + bucket_of(dv.w)], 1);
            atomicAdd(&histS[wave * 64 + bucket_of(sv.x)], 1);
            atomicAdd(&histS[wave * 64 + bucket_of(sv.y)], 1);
            atomicAdd(&histS[wave * 64 + bucket_of(sv.z)], 1);
            atomicAdd(&histS[wave * 64 + bucket_of(sv.w)], 1);
        }
        __syncthreads();
        if (tid < NRANGE) {
            int t = histD[tid] + histD[64 + tid] + histD[128 + tid] + histD[192 + tid];
            curD[tid] = atomicAdd(&cntD[ct * NRANGE + tid], t);
            int t2 = histS[tid] + histS[64 + tid] + histS[128 + tid] + histS[192 + tid];
            curS[tid] = atomicAdd(&cntS[ct * NRANGE + tid], t2);
        }
        __syncthreads();
        int* bD = binD + (size_t)ct * NRANGE * CAP;
        int* bS = binS + (size_t)ct * NRANGE * CAP;
#define EMIT2(ss, dd) { int pk = ((ss) << 15) | (dd); \
        unsigned bd = bucket_of(dd); int so = atomicAdd(&curD[bd], 1); \
        if (so < CAP) bD[bd * CAP + so] = pk; \
        unsigned bs = bucket_of(ss); int s2 = atomicAdd(&curS[bs], 1); \
        if (s2 < CAP) bS[bs * CAP + s2] = pk; }
        for (int i = tid; i < 1250; i += 256) {
            int4 dv = d4[base4 + i];
            int4 sv = s4[base4 + i];
            EMIT2(sv.x, dv.x); EMIT2(sv.y, dv.y); EMIT2(sv.z, dv.z); EMIT2(sv.w, dv.w);
        }
#undef EMIT2
    } else {
        // ---- role B: asad (LDS-transpose reduce, 2-node unroll) ----
        int idx = blockIdx.x - 1025;              // 0..1999
        int c = idx & 15;
        int start = (idx >> 4) * 160;             // 125 chunks x 160 nodes
        int lane = tid & 63;
        int wave = tid >> 6;
        float* A = smem;                          // [8][408] = 3264
        float* blk = smem + 3264;                 // [192]
        if (tid < 192) blk[tid] = 0.f;
        float u0[3], u1[3], u2[3], v0[3], v1[3], v2[3];
#pragma unroll
        for (int h = 0; h < 3; ++h) {
            u0[h] = U[c * 576 + h * 192 + lane];
            u1[h] = U[c * 576 + h * 192 + 64 + lane];
            u2[h] = U[c * 576 + h * 192 + 128 + lane];
            v0[h] = V[c * 576 + h * 192 + lane];
            v1[h] = V[c * 576 + h * 192 + 64 + lane];
            v2[h] = V[c * 576 + h * 192 + 128 + lane];
        }
        __syncthreads();
        const float* xc = x + (size_t)c * NN * 192;
        float* asn = a_s + (size_t)c * NN * 4;
        float* adn = a_d + (size_t)c * NN * 4;
        float m0 = 0.f, m1 = 0.f, m2 = 0.f;
        float* Aa = A + (wave * 2) * 408;
        float* Ab = A + (wave * 2 + 1) * 408;
        int rrow = lane >> 3, seg = lane & 7;
        for (int i = 0; i < 20; ++i) {
            int na = start + wave + 8 * i;
            int nb_ = na + 4;
            const float* xa = xc + (size_t)na * 192;
            const float* xb = xc + (size_t)nb_ * 192;
            float xa0 = xa[lane], xa1 = xa[64 + lane], xa2 = xa[128 + lane];
            float xb0 = xb[lane], xb1 = xb[64 + lane], xb2 = xb[128 + lane];
            m0 += xa0 + xb0; m1 += xa1 + xb1; m2 += xa2 + xb2;
            Aa[0 * 68 + lane] = xa0 * u0[0] + xa1 * u1[0] + xa2 * u2[0];
            Aa[1 * 68 + lane] = xa0 * u0[1] + xa1 * u1[1] + xa2 * u2[1];
            Aa[2 * 68 + lane] = xa0 * u0[2] + xa1 * u1[2] + xa2 * u2[2];
            Aa[3 * 68 + lane] = xa0 * v0[0] + xa1 * v1[0] + xa2 * v2[0];
            Aa[4 * 68 + lane] = xa0 * v0[1] + xa1 * v1[1] + xa2 * v2[1];
            Aa[5 * 68 + lane] = xa0 * v0[2] + xa1 * v1[2] + xa2 * v2[2];
            Ab[0 * 68 + lane] = xb0 * u0[0] + xb1 * u1[0] + xb2 * u2[0];
            Ab[1 * 68 + lane] = xb0 * u0[1] + xb1 * u1[1] + xb2 * u2[1];
            Ab[2 * 68 + lane] = xb0 * u0[2] + xb1 * u1[2] + xb2 * u2[2];
            Ab[3 * 68 + lane] = xb0 * v0[0] + xb1 * v1[0] + xb2 * v2[0];
            Ab[4 * 68 + lane] = xb0 * v0[1] + xb1 * v1[1] + xb2 * v2[1];
            Ab[5 * 68 + lane] = xb0 * v0[2] + xb1 * v1[2] + xb2 * v2[2];
            float sa = 0.f, sb = 0.f;
            if (lane < 48) {
                const float4* pa = (const float4*)(Aa + rrow * 68 + seg * 8);
                const float4* pb = (const float4*)(Ab + rrow * 68 + seg * 8);
                float4 a0 = pa[0], a1 = pa[1];
                float4 b0 = pb[0], b1 = pb[1];
                sa = ((a0.x + a0.y) + (a0.z + a0.w)) + ((a1.x + a1.y) + (a1.z + a1.w));
                sb = ((b0.x + b0.y) + (b0.z + b0.w)) + ((b1.x + b1.y) + (b1.z + b1.w));
            }
            sa += __shfl_xor(sa, 1, 64); sb += __shfl_xor(sb, 1, 64);
            sa += __shfl_xor(sa, 2, 64); sb += __shfl_xor(sb, 2, 64);
            sa += __shfl_xor(sa, 4, 64); sb += __shfl_xor(sb, 4, 64);
            if (lane < 48 && seg == 0) {
                if (rrow < 3) { asn[na * 4 + rrow] = sa;      asn[nb_ * 4 + rrow] = sb; }
                else          { adn[na * 4 + rrow - 3] = sa;  adn[nb_ * 4 + rrow - 3] = sb; }
            }
        }
        atomicAdd(&blk[lane], m0);
        atomicAdd(&blk[64 + lane], m1);
        atomicAdd(&blk[128 + lane], m2);
        __syncthreads();
        if (tid < 192) atomicAdd(&meanx[c * 192 + tid], blk[tid]);
    }
}

// XCD co-location for 1024-block edge kernels.
__device__ inline void map_ct(int wg, int& ct, int& j) {
    int xcd = wg & 7;
    ct = xcd * 2 + ((wg >> 3) & 1);
    j = wg >> 4;
}

// ---- K3: denom per dst-bucket (block-complete), scalar loop (unchanged).
__global__ __launch_bounds__(512) void k_eden_b(const int* __restrict__ bin,
        const int* __restrict__ cnt, const float* __restrict__ a_s,
        const float* __restrict__ a_d, float* __restrict__ comb) {
    int ct, bkt;
    map_ct(blockIdx.x, ct, bkt);
    int lo = bkt * NPR;
    int nnode = NN - lo < NPR ? NN - lo : NPR;
    int tid = threadIdx.x;
    __shared__ float adl[NPR * 3];
    __shared__ float den[NPR * 3];
    const float4* as4 = (const float4*)(a_s + (size_t)ct * NN * 4);
    const float4* ad4 = (const float4*)(a_d + (size_t)ct * NN * 4);
    for (int m = tid; m < nnode; m += 512) {
        float4 v = ad4[lo + m];
        adl[m * 3] = v.x; adl[m * 3 + 1] = v.y; adl[m * 3 + 2] = v.z;
    }
    for (int o = tid; o < nnode * 3; o += 512) den[o] = 0.f;
    __syncthreads();
    int n = cnt[ct * NRANGE + bkt]; if (n > CAP) n = CAP;
    const int* bc = bin + ((size_t)ct * NRANGE + bkt) * CAP;
    for (int i = tid; i < n; i += 512) {
        int v = bc[i];
        int d = v & 32767, s = v >> 15;
        int dl = d - lo;
        float4 av = as4[s];
        float e0 = av.x + adl[dl * 3];     e0 = e0 >= 0.f ? e0 : 0.2f * e0;
        float e1 = av.y + adl[dl * 3 + 1]; e1 = e1 >= 0.f ? e1 : 0.2f * e1;
        float e2 = av.z + adl[dl * 3 + 2]; e2 = e2 >= 0.f ? e2 : 0.2f * e2;
        atomicAdd(&den[dl * 3],     __expf(e0));
        atomicAdd(&den[dl * 3 + 1], __expf(e1));
        atomicAdd(&den[dl * 3 + 2], __expf(e2));
    }
    __syncthreads();
    float4* cb = (float4*)(comb + (size_t)ct * NN * 8);
    for (int m = tid; m < nnode; m += 512) {
        float d0 = den[m * 3], d1 = den[m * 3 + 1], d2 = den[m * 3 + 2];
        float4 a, b;
        a.x = adl[m * 3]; a.y = adl[m * 3 + 1]; a.z = adl[m * 3 + 2]; a.w = 0.f;
        b.x = d0 > 0.f ? 1.f / d0 : 0.f;
        b.y = d1 > 0.f ? 1.f / d1 : 0.f;
        b.z = d2 > 0.f ? 1.f / d2 : 0.f;
        b.w = 0.f;
        cb[(size_t)(lo + m) * 2]     = a;
        cb[(size_t)(lo + m) * 2 + 1] = b;
    }
}

// ---- K4: s per src-bucket (scalar) + scalar p-phase — exact R9 form.
__global__ __launch_bounds__(512) void k_es_p(const int* __restrict__ bin,
        const int* __restrict__ cnt, const float* __restrict__ a_s,
        const float* __restrict__ comb, const float* __restrict__ x,
        float* __restrict__ p) {
    int ct, bkt;
    map_ct(blockIdx.x, ct, bkt);
    int lo = bkt * NPR;
    int nnode = NN - lo < NPR ? NN - lo : NPR;
    int tid = threadIdx.x;
    __shared__ float asl[NPR * 3];
    __shared__ float sl[NPR * 3];
    __shared__ float blk[576];
    const float4* as4 = (const float4*)(a_s + (size_t)ct * NN * 4);
    const float4* cb  = (const float4*)(comb + (size_t)ct * NN * 8);
    for (int m = tid; m < nnode; m += 512) {
        float4 v = as4[lo + m];
        asl[m * 3] = v.x; asl[m * 3 + 1] = v.y; asl[m * 3 + 2] = v.z;
    }
    for (int o = tid; o < nnode * 3; o += 512) sl[o] = 0.f;
    for (int o = tid; o < 576; o += 512) blk[o] = 0.f;
    __syncthreads();
    int n = cnt[ct * NRANGE + bkt]; if (n > CAP) n = CAP;
    const int* bc = bin + ((size_t)ct * NRANGE + bkt) * CAP;
    for (int i = tid; i < n; i += 512) {
        int v = bc[i];
        int d = v & 32767, s = v >> 15;
        int slc = s - lo;
        float4 av = cb[(size_t)d * 2];       // a_d trio
        float4 dv = cb[(size_t)d * 2 + 1];   // reciprocal denominators
        float e0 = asl[slc * 3]     + av.x; e0 = e0 >= 0.f ? e0 : 0.2f * e0;
        float e1 = asl[slc * 3 + 1] + av.y; e1 = e1 >= 0.f ? e1 : 0.2f * e1;
        float e2 = asl[slc * 3 + 2] + av.z; e2 = e2 >= 0.f ? e2 : 0.2f * e2;
        atomicAdd(&sl[slc * 3],     __expf(e0) * dv.x);
        atomicAdd(&sl[slc * 3 + 1], __expf(e1) * dv.y);
        atomicAdd(&sl[slc * 3 + 2], __expf(e2) * dv.z);
    }
    __syncthreads();
    // p-phase: scalar streaming (64 lanes x 4B, 3 independent loads/row) —
    // empirically fastest (R5/R9 ~141us vs float4 variants 179-202us).
    int lane = tid & 63;
    int wave = tid >> 6;                 // 0..7
    const float* xc = x + (size_t)ct * NN * 192;
    float a00 = 0, a01 = 0, a02 = 0, a10 = 0, a11 = 0, a12 = 0, a20 = 0, a21 = 0, a22 = 0;
    for (int m = wave; m < nnode; m += 8) {
        float s0 = sl[m * 3], s1 = sl[m * 3 + 1], s2 = sl[m * 3 + 2];
        const float* xr = xc + (size_t)(lo + m) * 192;
        float x0 = xr[lane], x1 = xr[64 + lane], x2 = xr[128 + lane];
        a00 += s0 * x0; a01 += s0 * x1; a02 += s0 * x2;
        a10 += s1 * x0; a11 += s1 * x1; a12 += s1 * x2;
        a20 += s2 * x0; a21 += s2 * x1; a22 += s2 * x2;
    }
    atomicAdd(&blk[0 * 192 + lane], a00);
    atomicAdd(&blk[0 * 192 + 64 + lane], a01);
    atomicAdd(&blk[0 * 192 + 128 + lane], a02);
    atomicAdd(&blk[1 * 192 + lane], a10);
    atomicAdd(&blk[1 * 192 + 64 + lane], a11);
    atomicAdd(&blk[1 * 192 + 128 + lane], a12);
    atomicAdd(&blk[2 * 192 + lane], a20);
    atomicAdd(&blk[2 * 192 + 64 + lane], a21);
    atomicAdd(&blk[2 * 192 + 128 + lane], a22);
    __syncthreads();
    for (int o = tid; o < 576; o += 512) atomicAdd(&p[ct * 576 + o], blk[o]);
}

// ---- K6: assemble metagraph node features
__global__ __launch_bounds__(192) void k_mx(const float* __restrict__ mgx,
        const float* __restrict__ meanx, const float* __restrict__ p,
        const float* __restrict__ lin, const float* __restrict__ bias,
        float* __restrict__ mx) {
    int m = blockIdx.x, j = threadIdx.x;
    if (m < CT) {
        int h = j >> 6;
        const float* ph = p + m * 576 + h * 192;
        const float* L = lin + (size_t)m * 36864;
        float acc = 0.f;
        for (int k = 0; k < 192; ++k) acc += ph[k] * L[k * 192 + j];
        mx[m * 192 + j] = mgx[m * 192 + j] + (meanx[m * 192 + j] + acc) * (1.f / NN)
                          + bias[m * 192 + j];
    } else {
        mx[m * 192 + j] = mgx[m * 192 + j];
    }
}

// ---- K7b: apply W1^100 rows 16..47 to mx -> mx2 (rows 0..15 copied).
__global__ __launch_bounds__(192) void k_tapply(const float* __restrict__ W,
        const float* __restrict__ mx, float* __restrict__ mx2) {
    int m = blockIdx.x, j = threadIdx.x;
    if (m < CT) {
        mx2[m * 192 + j] = mx[m * 192 + j];
    } else {
        float acc = 0.f;
        for (int k = 0; k < 48; ++k) acc += W[m * 48 + k] * mx[k * 192 + j];
        mx2[m * 192 + j] = acc;
    }
}

// ---- K8a: hh[r][m][:] = mx2[m] @ meta_lin[r]
__global__ __launch_bounds__(192) void k_meta_h(const float* __restrict__ mx,
        const float* __restrict__ lin, float* __restrict__ hh) {
    int r = blockIdx.x, m = blockIdx.y, j = threadIdx.x;
    const float* L = lin + (size_t)r * 36864;
    const float* xr = mx + m * 192;
    float acc = 0.f;
    for (int k = 0; k < 192; ++k) acc += xr[k] * L[k * 192 + j];
    hh[((size_t)r * 48 + m) * 192 + j] = acc;
}

// ---- K8b: metagraph GAT edge softmax + aggregation
__global__ __launch_bounds__(256) void k_meta_edge(const float* __restrict__ hh,
        const float* __restrict__ att_s, const float* __restrict__ att_d,
        const float* __restrict__ bias, const int* __restrict__ edges,
        float* __restrict__ outs) {
    int r = blockIdx.x;
    int tid = threadIdx.x;
    __shared__ float as_[48][3], ad_[48][3], den[48][3];
    const float* hr = hh + (size_t)r * 48 * 192;
    float* og = outs + (size_t)r * 48 * 192;
    if (tid < 144) {
        int m = tid / 3, h = tid % 3;
        const float* As = att_s + r * 192 + h * 64;
        const float* Ad = att_d + r * 192 + h * 64;
        float s_ = 0.f, d_ = 0.f;
        for (int j = 0; j < 64; ++j) {
            float hv = hr[m * 192 + h * 64 + j];
            s_ += hv * As[j]; d_ += hv * Ad[j];
        }
        as_[m][h] = s_; ad_[m][h] = d_;
        den[m][h] = 0.f;
    }
    for (int o = tid; o < 9216; o += 256) og[o] = bias[r * 192 + (o % 192)];
    __syncthreads();
    int s = edges[(size_t)r * 2 * EMM + tid];
    int d = edges[(size_t)r * 2 * EMM + EMM + tid];
    float e0 = as_[s][0] + ad_[d][0]; e0 = e0 >= 0.f ? e0 : 0.2f * e0;
    float e1 = as_[s][1] + ad_[d][1]; e1 = e1 >= 0.f ? e1 : 0.2f * e1;
    float e2 = as_[s][2] + ad_[d][2]; e2 = e2 >= 0.f ? e2 : 0.2f * e2;
    float ex0 = __expf(e0), ex1 = __expf(e1), ex2 = __expf(e2);
    atomicAdd(&den[d][0], ex0);
    atomicAdd(&den[d][1], ex1);
    atomicAdd(&den[d][2], ex2);
    __syncthreads();
    float w0 = ex0 / den[d][0], w1 = ex1 / den[d][1], w2 = ex2 / den[d][2];
    const float* hs = hr + s * 192;
    float* od = og + d * 192;
    for (int j = 0; j < 64; ++j)        atomicAdd(&od[j], w0 * hs[j]);
    for (int j = 64; j < 128; ++j)      atomicAdd(&od[j], w1 * hs[j]);
    for (int j = 128; j < 192; ++j)     atomicAdd(&od[j], w2 * hs[j]);
}

// ---- K9: semantic attention; writes final output
__global__ __launch_bounds__(128) void k_sem(const float* __restrict__ outs,
        const float* __restrict__ W, const float* __restrict__ b,
        const float* __restrict__ q, float* __restrict__ out) {
    int m = blockIdx.x, s = threadIdx.x;
    __shared__ float ro[4][192];
    __shared__ float red[4][128];
    __shared__ float beta[4];
    for (int o = s; o < 768; o += 128) {
        int r = o / 192, d = o - r * 192;
        float v = outs[((size_t)r * 48 + m) * 192 + d];
        ro[r][d] = v > 0.f ? v : 0.f;
    }
    __syncthreads();
    float p0 = 0, p1 = 0, p2 = 0, p3 = 0;
    for (int d = 0; d < 192; ++d) {
        float wv = W[d * 128 + s];
        p0 += ro[0][d] * wv; p1 += ro[1][d] * wv; p2 += ro[2][d] * wv; p3 += ro[3][d] * wv;
    }
    float bb = b[s], qq = q[s];
    red[0][s] = tanhf(p0 + bb) * qq;
    red[1][s] = tanhf(p1 + bb) * qq;
    red[2][s] = tanhf(p2 + bb) * qq;
    red[3][s] = tanhf(p3 + bb) * qq;
    __syncthreads();
    for (int off = 64; off >= 1; off >>= 1) {
        if (s < off) {
            red[0][s] += red[0][s + off];
            red[1][s] += red[1][s + off];
            red[2][s] += red[2][s + off];
            red[3][s] += red[3][s + off];
        }
        __syncthreads();
    }
    if (s == 0) {
        float s0 = red[0][0], s1 = red[1][0], s2 = red[2][0], s3 = red[3][0];
        float mx4 = fmaxf(fmaxf(s0, s1), fmaxf(s2, s3));
        float e0 = __expf(s0 - mx4), e1 = __expf(s1 - mx4);
        float e2 = __expf(s2 - mx4), e3 = __expf(s3 - mx4);
        float inv = 1.f / (e0 + e1 + e2 + e3);
        beta[0] = e0 * inv; beta[1] = e1 * inv; beta[2] = e2 * inv; beta[3] = e3 * inv;
    }
    __syncthreads();
    for (int d = s; d < 192; d += 128) {
        float acc = ro[0][d] * beta[0] + ro[1][d] * beta[1]
                  + ro[2][d] * beta[2] + ro[3][d] * beta[3];
        out[m * 192 + d] = acc;
    }
}

extern "C" void kernel_launch(void* const* d_in, const int* in_sizes, int n_in,
                              void* d_out, int out_size, void* d_ws, size_t ws_size,
                              hipStream_t stream) {
    const float* ppi_x    = (const float*)d_in[0];
    const float* mgx      = (const float*)d_in[1];
    const float* ppi_lin  = (const float*)d_in[2];
    const float* ppi_as   = (const float*)d_in[3];
    const float* ppi_ad   = (const float*)d_in[4];
    const float* ppi_b    = (const float*)d_in[5];
    const float* meta_lin = (const float*)d_in[6];
    const float* meta_as  = (const float*)d_in[7];
    const float* meta_ad  = (const float*)d_in[8];
    const float* meta_b   = (const float*)d_in[9];
    const float* W_sem    = (const float*)d_in[10];
    const float* b_sem    = (const float*)d_in[11];
    const float* q_sem    = (const float*)d_in[12];
    const int*   ppi_e    = (const int*)d_in[13];
    const int*   meta_e   = (const int*)d_in[14];
    const int*   tnb      = (const int*)d_in[15];

    float* ws   = (float*)d_ws;
    float* mnx  = ws + OFF_MEANX;
    float* pac  = ws + OFF_P;
    int*   cntD = (int*)(ws + OFF_CNTD);
    int*   cntS = (int*)(ws + OFF_CNTS);
    float* comb = ws + OFF_COMB;
    float* a_s  = ws + OFF_AS;
    float* a_d  = ws + OFF_AD;
    float* U    = ws + OFF_U;
    float* V    = ws + OFF_V;
    float* mx   = ws + OFF_MX;
    float* hh   = ws + OFF_HH;
    float* outs = ws + OFF_OUTS;
    int*   binD = (int*)(ws + OFF_BIND);
    int*   binS = (int*)(ws + OFF_BINS);
    float* Wt   = ws + OFF_W;
    float* mx2  = ws + OFF_MX2;

    k_prep<<<16, 192, 0, stream>>>(ppi_lin, ppi_as, ppi_ad, U, V, ws);
    k_front<<<3025, 256, 0, stream>>>(ppi_e, cntD, cntS, binD, binS,
                                      ppi_x, U, V, a_s, a_d, mnx, tnb, Wt);
    k_eden_b<<<1024, 512, 0, stream>>>(binD, cntD, a_s, a_d, comb);
    k_es_p<<<1024, 512, 0, stream>>>(binS, cntS, a_s, comb, ppi_x, pac);
    k_mx<<<48, 192, 0, stream>>>(mgx, mnx, pac, ppi_lin, ppi_b, mx);
    k_tapply<<<48, 192, 0, stream>>>(Wt, mx, mx2);
    k_meta_h<<<dim3(4, 48), 192, 0, stream>>>(mx2, meta_lin, hh);
    k_meta_edge<<<4, 256, 0, stream>>>(hh, meta_as, meta_ad, meta_b, meta_e, outs);
    k_sem<<<48, 128, 0, stream>>>(outs, W_sem, b_sem, q_sem, (float*)d_out);
}

// Round 13
// 498.248 us; speedup vs baseline: 1.1921x; 1.1921x over previous
//
#include <hip/hip_runtime.h>

#define CT 16
#define NN 20000
#define EE 320000
#define MM 48
#define RR 4
#define EMM 256
#define NRANGE 64
#define NPR 313           // ceil(NN/64); buckets 0..62 have 313 nodes, bucket 63 has 281
#define CAP 5632          // per-bucket capacity (mean ~5008, sigma ~70 -> +9 sigma)
#define MAGIC 13721941ULL // ceil(2^32/313); floor(d/313) = (d*MAGIC)>>32, exact for d<2^20

// workspace layout (float offsets)
#define OFF_MEANX 0               // 3072
#define OFF_P     3072            // 9216 -> 12288
#define OFF_CNTD  12288           // CT*64 = 1024 ints
#define OFF_CNTS  13312           // 1024 ints -> 14336
#define ZERO_FLOATS 14336         // meanx+p+cnt zeroed by k_prep
#define OFF_COMB  14336           // CT*NN*8 ({a_d trio, 1/den trio} per node)
#define OFF_AS    2574336         // CT*NN*4
#define OFF_AD    3854336         // CT*NN*4
#define OFF_U     5134336         // 9216
#define OFF_V     5143552         // 9216
#define OFF_MX    5152768         // 9216
#define OFF_HH    5161984         // 36864
#define OFF_OUTS  5198848         // 36864
#define OFF_BIND  5235712         // CT*64*CAP ints
#define OFF_BINS  11002880        // CT*64*CAP ints
#define OFF_W     16770048        // 48*48 (W1^100; rows 16..47 written by k_front role C)
#define OFF_MX2   16772352        // 48*192 (tissue-applied mx)
// total = 16781568 floats = 67.1 MB

__device__ inline unsigned bucket_of(int d) {
    return (unsigned)(((unsigned long long)(unsigned)d * MAGIC) >> 32);
}

// ---- K1: fold att vectors through lin; also zeroes the small accumulators.
__global__ __launch_bounds__(192) void k_prep(const float* __restrict__ lin,
        const float* __restrict__ as_g, const float* __restrict__ ad_g,
        float* __restrict__ U, float* __restrict__ V, float* __restrict__ zws) {
    int c = blockIdx.x, d = threadIdx.x;
    int gt = c * 192 + d;
    for (int o = gt; o < ZERO_FLOATS; o += 16 * 192) zws[o] = 0.f;
    const float* L  = lin + ((size_t)c * 192 + d) * 192;
    const float* As = as_g + c * 192;
    const float* Ad = ad_g + c * 192;
#pragma unroll
    for (int h = 0; h < 3; ++h) {
        float u = 0.f, v = 0.f;
        for (int j = 0; j < 64; ++j) {
            float lv = L[h * 64 + j];
            u += lv * As[h * 64 + j];
            v += lv * Ad[h * 64 + j];
        }
        U[c * 576 + h * 192 + d] = u;
        V[c * 576 + h * 192 + d] = v;
    }
}

// ---- K_front: fused independent front work + tissue W1^100 (role C, block 0).
// __launch_bounds__(256, 8) caps VGPR at 64 so role C's branch cannot
// deflate role A/B occupancy (R12 lesson: branch max VGPR=188 -> 11% occ).
// Role C is register-lean: 3x[32][48] LDS ping-pong, rolled loops.
__global__ __launch_bounds__(256, 8) void k_front(const int* __restrict__ edges,
        int* __restrict__ cntD, int* __restrict__ cntS,
        int* __restrict__ binD, int* __restrict__ binS,
        const float* __restrict__ x, const float* __restrict__ U,
        const float* __restrict__ V, float* __restrict__ a_s,
        float* __restrict__ a_d, float* __restrict__ meanx,
        const int* __restrict__ nb, float* __restrict__ Wout) {
    __shared__ __align__(16) float smem[4608];   // 18.4 KB (role C: 3x1536)
    int tid = threadIdx.x;
    if (blockIdx.x == 0) {
        // ---- role C: W1^100, bottom 32x48 block only (rows 0..15 stay identity).
        // C[i,j] = A[i,j]*[j<16] + sum_t A[i,16+t]*B[t,j], 3-buffer ping-pong.
        float* B0 = smem;
        float* B1 = smem + 1536;
        float* B2 = smem + 3072;
        float* B[3] = {B0, B1, B2};
        for (int o = tid; o < 1536; o += 256) {
            int i = o / 48, j = o - i * 48;
            float idv = (j == 16 + i) ? 1.f : 0.f;
            B0[o] = idv;           // P: pre-sweep identity bottom
            B1[o] = idv;           // R = I (bottom block)
        }
        __syncthreads();
        if (tid < 48) {
            int j = tid;  // lane owns column j: Gauss-Seidel deps intra-lane
            for (int t = 0; t < 32; ++t) {
                float acc = 0.f;
                for (int k = 0; k < 8; ++k) {
                    int idx = nb[t * 8 + k];
                    acc += (idx < 16) ? (j == idx ? 1.f : 0.f)
                                      : B0[(idx - 16) * 48 + j];
                }
                B0[t * 48 + j] = acc * 0.125f;
            }
        }
        __syncthreads();
        int iP = 0, iR = 1, iT = 2;
        int e = 100;
        while (e) {
            if (e & 1) {  // R(iT) = R(iR) x P(iP)
                for (int o = tid; o < 1536; o += 256) {
                    int i = o / 48, j = o - i * 48;
                    float acc = (j < 16) ? B[iR][i * 48 + j] : 0.f;
                    for (int t = 0; t < 32; ++t)
                        acc += B[iR][i * 48 + 16 + t] * B[iP][t * 48 + j];
                    B[iT][o] = acc;
                }
                __syncthreads();
                int t_ = iR; iR = iT; iT = t_;
            }
            e >>= 1;
            if (e) {      // P(iT) = P(iP) x P(iP)
                for (int o = tid; o < 1536; o += 256) {
                    int i = o / 48, j = o - i * 48;
                    float acc = (j < 16) ? B[iP][i * 48 + j] : 0.f;
                    for (int t = 0; t < 32; ++t)
                        acc += B[iP][i * 48 + 16 + t] * B[iP][t * 48 + j];
                    B[iT][o] = acc;
                }
                __syncthreads();
                int t_ = iP; iP = iT; iT = t_;
            }
        }
        for (int o = tid; o < 1536; o += 256) {
            int i = o / 48, j = o - i * 48;
            Wout[(16 + i) * 48 + j] = B[iR][o];   // only rows 16..47 consumed
        }
    } else if (blockIdx.x < 1025) {
        // ---- role A: bin2 ----
        int wg = blockIdx.x - 1;
        int ct = (wg & 7) * 2 + ((wg >> 3) & 1);  // XCD-pinned celltype
        int part = wg >> 4;                       // 0..63, chunk = 5000 edges
        int wave = tid >> 6;
        int* histD = (int*)smem;                  // [4][64]
        int* histS = histD + 256;                 // [4][64]
        int* curD  = histS + 256;                 // [64]
        int* curS  = curD + 64;                   // [64]
        if (tid < NRANGE) {
            histD[0 * 64 + tid] = 0; histD[1 * 64 + tid] = 0;
            histD[2 * 64 + tid] = 0; histD[3 * 64 + tid] = 0;
            histS[0 * 64 + tid] = 0; histS[1 * 64 + tid] = 0;
            histS[2 * 64 + tid] = 0; histS[3 * 64 + tid] = 0;
        }
        __syncthreads();
        const int* srcp = edges + (size_t)ct * 2 * EE;
        const int* dstp = srcp + EE;
        const int4* s4 = (const int4*)srcp;
        const int4* d4 = (const int4*)dstp;
        int base4 = part * 1250;
        for (int i = tid; i < 1250; i += 256) {
            int4 dv = d4[base4 + i];
            int4 sv = s4[base4 + i];
            atomicAdd(&histD[wave * 64 + bucket_of(dv.x)], 1);
            atomicAdd(&histD[wave * 64 + bucket_of(dv.y)], 1);
            atomicAdd(&histD[wave * 64 + bucket_of(dv.z)], 1);
            atomicAdd(&histD[wave * 64 + bucket_of(dv.w)], 1);
            atomicAdd(&histS[wave * 64 + bucket_of(sv.x)], 1);
            atomicAdd(&histS[wave * 64 + bucket_of(sv.y)], 1);
            atomicAdd(&histS[wave * 64 + bucket_of(sv.z)], 1);
            atomicAdd(&histS[wave * 64 + bucket_of(sv.w)], 1);
        }
        __syncthreads();
        if (tid < NRANGE) {
            int t = histD[tid] + histD[64 + tid] + histD[128 + tid] + histD[192 + tid];
            curD[tid] = atomicAdd(&cntD[ct * NRANGE + tid], t);
            int t2 = histS[tid] + histS[64 + tid] + histS[128 + tid] + histS[192 + tid];
            curS[tid] = atomicAdd(&cntS[ct * NRANGE + tid], t2);
        }
        __syncthreads();
        int* bD = binD + (size_t)ct * NRANGE * CAP;
        int* bS = binS + (size_t)ct * NRANGE * CAP;
#define EMIT2(ss, dd) { int pk = ((ss) << 15) | (dd); \
        unsigned bd = bucket_of(dd); int so = atomicAdd(&curD[bd], 1); \
        if (so < CAP) bD[bd * CAP + so] = pk; \
        unsigned bs = bucket_of(ss); int s2 = atomicAdd(&curS[bs], 1); \
        if (s2 < CAP) bS[bs * CAP + s2] = pk; }
        for (int i = tid; i < 1250; i += 256) {
            int4 dv = d4[base4 + i];
            int4 sv = s4[base4 + i];
            EMIT2(sv.x, dv.x); EMIT2(sv.y, dv.y); EMIT2(sv.z, dv.z); EMIT2(sv.w, dv.w);
        }
#undef EMIT2
    } else {
        // ---- role B: asad (LDS-transpose reduce, 2-node unroll) ----
        int idx = blockIdx.x - 1025;              // 0..1999
        int c = idx & 15;
        int start = (idx >> 4) * 160;             // 125 chunks x 160 nodes
        int lane = tid & 63;
        int wave = tid >> 6;
        float* A = smem;                          // [8][408] = 3264
        float* blk = smem + 3264;                 // [192]
        if (tid < 192) blk[tid] = 0.f;
        float u0[3], u1[3], u2[3], v0[3], v1[3], v2[3];
#pragma unroll
        for (int h = 0; h < 3; ++h) {
            u0[h] = U[c * 576 + h * 192 + lane];
            u1[h] = U[c * 576 + h * 192 + 64 + lane];
            u2[h] = U[c * 576 + h * 192 + 128 + lane];
            v0[h] = V[c * 576 + h * 192 + lane];
            v1[h] = V[c * 576 + h * 192 + 64 + lane];
            v2[h] = V[c * 576 + h * 192 + 128 + lane];
        }
        __syncthreads();
        const float* xc = x + (size_t)c * NN * 192;
        float* asn = a_s + (size_t)c * NN * 4;
        float* adn = a_d + (size_t)c * NN * 4;
        float m0 = 0.f, m1 = 0.f, m2 = 0.f;
        float* Aa = A + (wave * 2) * 408;
        float* Ab = A + (wave * 2 + 1) * 408;
        int rrow = lane >> 3, seg = lane & 7;
        for (int i = 0; i < 20; ++i) {
            int na = start + wave + 8 * i;
            int nb_ = na + 4;
            const float* xa = xc + (size_t)na * 192;
            const float* xb = xc + (size_t)nb_ * 192;
            float xa0 = xa[lane], xa1 = xa[64 + lane], xa2 = xa[128 + lane];
            float xb0 = xb[lane], xb1 = xb[64 + lane], xb2 = xb[128 + lane];
            m0 += xa0 + xb0; m1 += xa1 + xb1; m2 += xa2 + xb2;
            Aa[0 * 68 + lane] = xa0 * u0[0] + xa1 * u1[0] + xa2 * u2[0];
            Aa[1 * 68 + lane] = xa0 * u0[1] + xa1 * u1[1] + xa2 * u2[1];
            Aa[2 * 68 + lane] = xa0 * u0[2] + xa1 * u1[2] + xa2 * u2[2];
            Aa[3 * 68 + lane] = xa0 * v0[0] + xa1 * v1[0] + xa2 * v2[0];
            Aa[4 * 68 + lane] = xa0 * v0[1] + xa1 * v1[1] + xa2 * v2[1];
            Aa[5 * 68 + lane] = xa0 * v0[2] + xa1 * v1[2] + xa2 * v2[2];
            Ab[0 * 68 + lane] = xb0 * u0[0] + xb1 * u1[0] + xb2 * u2[0];
            Ab[1 * 68 + lane] = xb0 * u0[1] + xb1 * u1[1] + xb2 * u2[1];
            Ab[2 * 68 + lane] = xb0 * u0[2] + xb1 * u1[2] + xb2 * u2[2];
            Ab[3 * 68 + lane] = xb0 * v0[0] + xb1 * v1[0] + xb2 * v2[0];
            Ab[4 * 68 + lane] = xb0 * v0[1] + xb1 * v1[1] + xb2 * v2[1];
            Ab[5 * 68 + lane] = xb0 * v0[2] + xb1 * v1[2] + xb2 * v2[2];
            float sa = 0.f, sb = 0.f;
            if (lane < 48) {
                const float4* pa = (const float4*)(Aa + rrow * 68 + seg * 8);
                const float4* pb = (const float4*)(Ab + rrow * 68 + seg * 8);
                float4 a0 = pa[0], a1 = pa[1];
                float4 b0 = pb[0], b1 = pb[1];
                sa = ((a0.x + a0.y) + (a0.z + a0.w)) + ((a1.x + a1.y) + (a1.z + a1.w));
                sb = ((b0.x + b0.y) + (b0.z + b0.w)) + ((b1.x + b1.y) + (b1.z + b1.w));
            }
            sa += __shfl_xor(sa, 1, 64); sb += __shfl_xor(sb, 1, 64);
            sa += __shfl_xor(sa, 2, 64); sb += __shfl_xor(sb, 2, 64);
            sa += __shfl_xor(sa, 4, 64); sb += __shfl_xor(sb, 4, 64);
            if (lane < 48 && seg == 0) {
                if (rrow < 3) { asn[na * 4 + rrow] = sa;      asn[nb_ * 4 + rrow] = sb; }
                else          { adn[na * 4 + rrow - 3] = sa;  adn[nb_ * 4 + rrow - 3] = sb; }
            }
        }
        atomicAdd(&blk[lane], m0);
        atomicAdd(&blk[64 + lane], m1);
        atomicAdd(&blk[128 + lane], m2);
        __syncthreads();
        if (tid < 192) atomicAdd(&meanx[c * 192 + tid], blk[tid]);
    }
}

// XCD co-location for 1024-block edge kernels.
__device__ inline void map_ct(int wg, int& ct, int& j) {
    int xcd = wg & 7;
    ct = xcd * 2 + ((wg >> 3) & 1);
    j = wg >> 4;
}

// ---- K3: denom per dst-bucket (block-complete), scalar loop (unchanged).
__global__ __launch_bounds__(512) void k_eden_b(const int* __restrict__ bin,
        const int* __restrict__ cnt, const float* __restrict__ a_s,
        const float* __restrict__ a_d, float* __restrict__ comb) {
    int ct, bkt;
    map_ct(blockIdx.x, ct, bkt);
    int lo = bkt * NPR;
    int nnode = NN - lo < NPR ? NN - lo : NPR;
    int tid = threadIdx.x;
    __shared__ float adl[NPR * 3];
    __shared__ float den[NPR * 3];
    const float4* as4 = (const float4*)(a_s + (size_t)ct * NN * 4);
    const float4* ad4 = (const float4*)(a_d + (size_t)ct * NN * 4);
    for (int m = tid; m < nnode; m += 512) {
        float4 v = ad4[lo + m];
        adl[m * 3] = v.x; adl[m * 3 + 1] = v.y; adl[m * 3 + 2] = v.z;
    }
    for (int o = tid; o < nnode * 3; o += 512) den[o] = 0.f;
    __syncthreads();
    int n = cnt[ct * NRANGE + bkt]; if (n > CAP) n = CAP;
    const int* bc = bin + ((size_t)ct * NRANGE + bkt) * CAP;
    for (int i = tid; i < n; i += 512) {
        int v = bc[i];
        int d = v & 32767, s = v >> 15;
        int dl = d - lo;
        float4 av = as4[s];
        float e0 = av.x + adl[dl * 3];     e0 = e0 >= 0.f ? e0 : 0.2f * e0;
        float e1 = av.y + adl[dl * 3 + 1]; e1 = e1 >= 0.f ? e1 : 0.2f * e1;
        float e2 = av.z + adl[dl * 3 + 2]; e2 = e2 >= 0.f ? e2 : 0.2f * e2;
        atomicAdd(&den[dl * 3],     __expf(e0));
        atomicAdd(&den[dl * 3 + 1], __expf(e1));
        atomicAdd(&den[dl * 3 + 2], __expf(e2));
    }
    __syncthreads();
    float4* cb = (float4*)(comb + (size_t)ct * NN * 8);
    for (int m = tid; m < nnode; m += 512) {
        float d0 = den[m * 3], d1 = den[m * 3 + 1], d2 = den[m * 3 + 2];
        float4 a, b;
        a.x = adl[m * 3]; a.y = adl[m * 3 + 1]; a.z = adl[m * 3 + 2]; a.w = 0.f;
        b.x = d0 > 0.f ? 1.f / d0 : 0.f;
        b.y = d1 > 0.f ? 1.f / d1 : 0.f;
        b.z = d2 > 0.f ? 1.f / d2 : 0.f;
        b.w = 0.f;
        cb[(size_t)(lo + m) * 2]     = a;
        cb[(size_t)(lo + m) * 2 + 1] = b;
    }
}

// ---- K4: s per src-bucket (scalar) + scalar p-phase — exact R9 form.
__global__ __launch_bounds__(512) void k_es_p(const int* __restrict__ bin,
        const int* __restrict__ cnt, const float* __restrict__ a_s,
        const float* __restrict__ comb, const float* __restrict__ x,
        float* __restrict__ p) {
    int ct, bkt;
    map_ct(blockIdx.x, ct, bkt);
    int lo = bkt * NPR;
    int nnode = NN - lo < NPR ? NN - lo : NPR;
    int tid = threadIdx.x;
    __shared__ float asl[NPR * 3];
    __shared__ float sl[NPR * 3];
    __shared__ float blk[576];
    const float4* as4 = (const float4*)(a_s + (size_t)ct * NN * 4);
    const float4* cb  = (const float4*)(comb + (size_t)ct * NN * 8);
    for (int m = tid; m < nnode; m += 512) {
        float4 v = as4[lo + m];
        asl[m * 3] = v.x; asl[m * 3 + 1] = v.y; asl[m * 3 + 2] = v.z;
    }
    for (int o = tid; o < nnode * 3; o += 512) sl[o] = 0.f;
    for (int o = tid; o < 576; o += 512) blk[o] = 0.f;
    __syncthreads();
    int n = cnt[ct * NRANGE + bkt]; if (n > CAP) n = CAP;
    const int* bc = bin + ((size_t)ct * NRANGE + bkt) * CAP;
    for (int i = tid; i < n; i += 512) {
        int v = bc[i];
        int d = v & 32767, s = v >> 15;
        int slc = s - lo;
        float4 av = cb[(size_t)d * 2];       // a_d trio
        float4 dv = cb[(size_t)d * 2 + 1];   // reciprocal denominators
        float e0 = asl[slc * 3]     + av.x; e0 = e0 >= 0.f ? e0 : 0.2f * e0;
        float e1 = asl[slc * 3 + 1] + av.y; e1 = e1 >= 0.f ? e1 : 0.2f * e1;
        float e2 = asl[slc * 3 + 2] + av.z; e2 = e2 >= 0.f ? e2 : 0.2f * e2;
        atomicAdd(&sl[slc * 3],     __expf(e0) * dv.x);
        atomicAdd(&sl[slc * 3 + 1], __expf(e1) * dv.y);
        atomicAdd(&sl[slc * 3 + 2], __expf(e2) * dv.z);
    }
    __syncthreads();
    // p-phase: scalar streaming (64 lanes x 4B, 3 independent loads/row) —
    // empirically fastest (R5/R9 ~141us vs float4 variants 179-202us).
    int lane = tid & 63;
    int wave = tid >> 6;                 // 0..7
    const float* xc = x + (size_t)ct * NN * 192;
    float a00 = 0, a01 = 0, a02 = 0, a10 = 0, a11 = 0, a12 = 0, a20 = 0, a21 = 0, a22 = 0;
    for (int m = wave; m < nnode; m += 8) {
        float s0 = sl[m * 3], s1 = sl[m * 3 + 1], s2 = sl[m * 3 + 2];
        const float* xr = xc + (size_t)(lo + m) * 192;
        float x0 = xr[lane], x1 = xr[64 + lane], x2 = xr[128 + lane];
        a00 += s0 * x0; a01 += s0 * x1; a02 += s0 * x2;
        a10 += s1 * x0; a11 += s1 * x1; a12 += s1 * x2;
        a20 += s2 * x0; a21 += s2 * x1; a22 += s2 * x2;
    }
    atomicAdd(&blk[0 * 192 + lane], a00);
    atomicAdd(&blk[0 * 192 + 64 + lane], a01);
    atomicAdd(&blk[0 * 192 + 128 + lane], a02);
    atomicAdd(&blk[1 * 192 + lane], a10);
    atomicAdd(&blk[1 * 192 + 64 + lane], a11);
    atomicAdd(&blk[1 * 192 + 128 + lane], a12);
    atomicAdd(&blk[2 * 192 + lane], a20);
    atomicAdd(&blk[2 * 192 + 64 + lane], a21);
    atomicAdd(&blk[2 * 192 + 128 + lane], a22);
    __syncthreads();
    for (int o = tid; o < 576; o += 512) atomicAdd(&p[ct * 576 + o], blk[o]);
}

// ---- K6: assemble metagraph node features
__global__ __launch_bounds__(192) void k_mx(const float* __restrict__ mgx,
        const float* __restrict__ meanx, const float* __restrict__ p,
        const float* __restrict__ lin, const float* __restrict__ bias,
        float* __restrict__ mx) {
    int m = blockIdx.x, j = threadIdx.x;
    if (m < CT) {
        int h = j >> 6;
        const float* ph = p + m * 576 + h * 192;
        const float* L = lin + (size_t)m * 36864;
        float acc = 0.f;
        for (int k = 0; k < 192; ++k) acc += ph[k] * L[k * 192 + j];
        mx[m * 192 + j] = mgx[m * 192 + j] + (meanx[m * 192 + j] + acc) * (1.f / NN)
                          + bias[m * 192 + j];
    } else {
        mx[m * 192 + j] = mgx[m * 192 + j];
    }
}

// ---- K7b: apply W1^100 rows 16..47 to mx -> mx2 (rows 0..15 copied).
__global__ __launch_bounds__(192) void k_tapply(const float* __restrict__ W,
        const float* __restrict__ mx, float* __restrict__ mx2) {
    int m = blockIdx.x, j = threadIdx.x;
    if (m < CT) {
        mx2[m * 192 + j] = mx[m * 192 + j];
    } else {
        float acc = 0.f;
        for (int k = 0; k < 48; ++k) acc += W[m * 48 + k] * mx[k * 192 + j];
        mx2[m * 192 + j] = acc;
    }
}

// ---- K8a: hh[r][m][:] = mx2[m] @ meta_lin[r]
__global__ __launch_bounds__(192) void k_meta_h(const float* __restrict__ mx,
        const float* __restrict__ lin, float* __restrict__ hh) {
    int r = blockIdx.x, m = blockIdx.y, j = threadIdx.x;
    const float* L = lin + (size_t)r * 36864;
    const float* xr = mx + m * 192;
    float acc = 0.f;
    for (int k = 0; k < 192; ++k) acc += xr[k] * L[k * 192 + j];
    hh[((size_t)r * 48 + m) * 192 + j] = acc;
}

// ---- K8b: metagraph GAT edge softmax + aggregation
__global__ __launch_bounds__(256) void k_meta_edge(const float* __restrict__ hh,
        const float* __restrict__ att_s, const float* __restrict__ att_d,
        const float* __restrict__ bias, const int* __restrict__ edges,
        float* __restrict__ outs) {
    int r = blockIdx.x;
    int tid = threadIdx.x;
    __shared__ float as_[48][3], ad_[48][3], den[48][3];
    const float* hr = hh + (size_t)r * 48 * 192;
    float* og = outs + (size_t)r * 48 * 192;
    if (tid < 144) {
        int m = tid / 3, h = tid % 3;
        const float* As = att_s + r * 192 + h * 64;
        const float* Ad = att_d + r * 192 + h * 64;
        float s_ = 0.f, d_ = 0.f;
        for (int j = 0; j < 64; ++j) {
            float hv = hr[m * 192 + h * 64 + j];
            s_ += hv * As[j]; d_ += hv * Ad[j];
        }
        as_[m][h] = s_; ad_[m][h] = d_;
        den[m][h] = 0.f;
    }
    for (int o = tid; o < 9216; o += 256) og[o] = bias[r * 192 + (o % 192)];
    __syncthreads();
    int s = edges[(size_t)r * 2 * EMM + tid];
    int d = edges[(size_t)r * 2 * EMM + EMM + tid];
    float e0 = as_[s][0] + ad_[d][0]; e0 = e0 >= 0.f ? e0 : 0.2f * e0;
    float e1 = as_[s][1] + ad_[d][1]; e1 = e1 >= 0.f ? e1 : 0.2f * e1;
    float e2 = as_[s][2] + ad_[d][2]; e2 = e2 >= 0.f ? e2 : 0.2f * e2;
    float ex0 = __expf(e0), ex1 = __expf(e1), ex2 = __expf(e2);
    atomicAdd(&den[d][0], ex0);
    atomicAdd(&den[d][1], ex1);
    atomicAdd(&den[d][2], ex2);
    __syncthreads();
    float w0 = ex0 / den[d][0], w1 = ex1 / den[d][1], w2 = ex2 / den[d][2];
    const float* hs = hr + s * 192;
    float* od = og + d * 192;
    for (int j = 0; j < 64; ++j)        atomicAdd(&od[j], w0 * hs[j]);
    for (int j = 64; j < 128; ++j)      atomicAdd(&od[j], w1 * hs[j]);
    for (int j = 128; j < 192; ++j)     atomicAdd(&od[j], w2 * hs[j]);
}

// ---- K9: semantic attention; writes final output
__global__ __launch_bounds__(128) void k_sem(const float* __restrict__ outs,
        const float* __restrict__ W, const float* __restrict__ b,
        const float* __restrict__ q, float* __restrict__ out) {
    int m = blockIdx.x, s = threadIdx.x;
    __shared__ float ro[4][192];
    __shared__ float red[4][128];
    __shared__ float beta[4];
    for (int o = s; o < 768; o += 128) {
        int r = o / 192, d = o - r * 192;
        float v = outs[((size_t)r * 48 + m) * 192 + d];
        ro[r][d] = v > 0.f ? v : 0.f;
    }
    __syncthreads();
    float p0 = 0, p1 = 0, p2 = 0, p3 = 0;
    for (int d = 0; d < 192; ++d) {
        float wv = W[d * 128 + s];
        p0 += ro[0][d] * wv; p1 += ro[1][d] * wv; p2 += ro[2][d] * wv; p3 += ro[3][d] * wv;
    }
    float bb = b[s], qq = q[s];
    red[0][s] = tanhf(p0 + bb) * qq;
    red[1][s] = tanhf(p1 + bb) * qq;
    red[2][s] = tanhf(p2 + bb) * qq;
    red[3][s] = tanhf(p3 + bb) * qq;
    __syncthreads();
    for (int off = 64; off >= 1; off >>= 1) {
        if (s < off) {
            red[0][s] += red[0][s + off];
            red[1][s] += red[1][s + off];
            red[2][s] += red[2][s + off];
            red[3][s] += red[3][s + off];
        }
        __syncthreads();
    }
    if (s == 0) {
        float s0 = red[0][0], s1 = red[1][0], s2 = red[2][0], s3 = red[3][0];
        float mx4 = fmaxf(fmaxf(s0, s1), fmaxf(s2, s3));
        float e0 = __expf(s0 - mx4), e1 = __expf(s1 - mx4);
        float e2 = __expf(s2 - mx4), e3 = __expf(s3 - mx4);
        float inv = 1.f / (e0 + e1 + e2 + e3);
        beta[0] = e0 * inv; beta[1] = e1 * inv; beta[2] = e2 * inv; beta[3] = e3 * inv;
    }
    __syncthreads();
    for (int d = s; d < 192; d += 128) {
        float acc = ro[0][d] * beta[0] + ro[1][d] * beta[1]
                  + ro[2][d] * beta[2] + ro[3][d] * beta[3];
        out[m * 192 + d] = acc;
    }
}

extern "C" void kernel_launch(void* const* d_in, const int* in_sizes, int n_in,
                              void* d_out, int out_size, void* d_ws, size_t ws_size,
                              hipStream_t stream) {
    const float* ppi_x    = (const float*)d_in[0];
    const float* mgx      = (const float*)d_in[1];
    const float* ppi_lin  = (const float*)d_in[2];
    const float* ppi_as   = (const float*)d_in[3];
    const float* ppi_ad   = (const float*)d_in[4];
    const float* ppi_b    = (const float*)d_in[5];
    const float* meta_lin = (const float*)d_in[6];
    const float* meta_as  = (const float*)d_in[7];
    const float* meta_ad  = (const float*)d_in[8];
    const float* meta_b   = (const float*)d_in[9];
    const float* W_sem    = (const float*)d_in[10];
    const float* b_sem    = (const float*)d_in[11];
    const float* q_sem    = (const float*)d_in[12];
    const int*   ppi_e    = (const int*)d_in[13];
    const int*   meta_e   = (const int*)d_in[14];
    const int*   tnb      = (const int*)d_in[15];

    float* ws   = (float*)d_ws;
    float* mnx  = ws + OFF_MEANX;
    float* pac  = ws + OFF_P;
    int*   cntD = (int*)(ws + OFF_CNTD);
    int*   cntS = (int*)(ws + OFF_CNTS);
    float* comb = ws + OFF_COMB;
    float* a_s  = ws + OFF_AS;
    float* a_d  = ws + OFF_AD;
    float* U    = ws + OFF_U;
    float* V    = ws + OFF_V;
    float* mx   = ws + OFF_MX;
    float* hh   = ws + OFF_HH;
    float* outs = ws + OFF_OUTS;
    int*   binD = (int*)(ws + OFF_BIND);
    int*   binS = (int*)(ws + OFF_BINS);
    float* Wt   = ws + OFF_W;
    float* mx2  = ws + OFF_MX2;

    k_prep<<<16, 192, 0, stream>>>(ppi_lin, ppi_as, ppi_ad, U, V, ws);
    k_front<<<3025, 256, 0, stream>>>(ppi_e, cntD, cntS, binD, binS,
                                      ppi_x, U, V, a_s, a_d, mnx, tnb, Wt);
    k_eden_b<<<1024, 512, 0, stream>>>(binD, cntD, a_s, a_d, comb);
    k_es_p<<<1024, 512, 0, stream>>>(binS, cntS, a_s, comb, ppi_x, pac);
    k_mx<<<48, 192, 0, stream>>>(mgx, mnx, pac, ppi_lin, ppi_b, mx);
    k_tapply<<<48, 192, 0, stream>>>(Wt, mx, mx2);
    k_meta_h<<<dim3(4, 48), 192, 0, stream>>>(mx2, meta_lin, hh);
    k_meta_edge<<<4, 256, 0, stream>>>(hh, meta_as, meta_ad, meta_b, meta_e, outs);
    k_sem<<<48, 128, 0, stream>>>(outs, W_sem, b_sem, q_sem, (float*)d_out);
}